// Round 3
// baseline (334.832 us; speedup 1.0000x reference)
//
#include <hip/hip_runtime.h>
#include <hip/hip_cooperative_groups.h>
#include <stdint.h>

namespace cg = cooperative_groups;
typedef unsigned long long u64;

// Geometry: 2 batches x 64 depth x 256 x 256 = 8388608 pixels = 131072 u64 words.
#define SLICES 128
#define WPS 1024                     // u64 words per slice
#define TOTAL_WORDS (SLICES * WPS)   // 131072
#define NBLK 512                     // 512 blocks x 256 threads = 131072 threads (1 word/thread)

// Single cooperative kernel. ws: mbits (1MB) | planes[5] (5MB) | partials (512*3 f32).
// d0 identity: sum_{k=0..20} dilate^k(edge) = max(0, 21-d0), d0 = Chebyshev dist
// to nearest edge in-slice => dist = (min(d0,21)+1)/22, weight lookup (22 entries).
__global__ __launch_bounds__(256) void bbsd_all(const float* __restrict__ outputs,
                                                const int* __restrict__ masks,
                                                u64* __restrict__ mbits,
                                                u64* __restrict__ planes,
                                                float* __restrict__ partials,
                                                float* __restrict__ out) {
    __shared__ u64 rows[256][5];   // [row][word], 5th col = pad
    __shared__ u64 tmp[256][5];
    __shared__ float wtab[22];
    __shared__ float red[4][8];

    cg::grid_group grid = cg::this_grid();
    const int t = threadIdx.x;
    const int lane = t & 63, wv = t >> 6;
    const int tid = blockIdx.x * 256 + t;   // owns pixel range [tid*64, tid*64+64)

    // ---- phase A: pack 64 mask ints -> one u64 per thread (16 independent int4 loads) ----
    u64 mword = 0;
    {
        const int4* mp = (const int4*)masks + (size_t)tid * 16;
        #pragma unroll
        for (int j = 0; j < 16; ++j) {
            int4 v = mp[j];
            u64 b = (u64)(v.x != 0) | ((u64)(v.y != 0) << 1)
                  | ((u64)(v.z != 0) << 2) | ((u64)(v.w != 0) << 3);
            mword |= b << (j * 4);
        }
        mbits[tid] = mword;
    }
    grid.sync();

    // ---- phase B: per-slice edge + cascaded dilation, d0 as 5 bit-planes (blocks 0..127) ----
    if (blockIdx.x < SLICES) {
        const u64* mb = mbits + (size_t)blockIdx.x * WPS;
        u64 m[4];
        #pragma unroll
        for (int j = 0; j < 4; ++j) { m[j] = mb[t * 4 + j]; rows[t][j] = m[j]; }
        __syncthreads();

        u64 c[4];
        {
            u64 up[4], dn[4];
            #pragma unroll
            for (int j = 0; j < 4; ++j) {
                up[j] = (t > 0)   ? rows[t - 1][j] : 0ull;
                dn[j] = (t < 255) ? rows[t + 1][j] : 0ull;
            }
            #pragma unroll
            for (int j = 0; j < 4; ++j) {
                u64 lf = (m[j] << 1) | (j > 0 ? (m[j - 1] >> 63) : 0ull);
                u64 rt = (m[j] >> 1) | (j < 3 ? (m[j + 1] << 63) : 0ull);
                c[j] = m[j] & ~(up[j] & dn[j] & lf & rt);   // edge (zero-padded)
            }
        }

        u64 p[5][4];
        #pragma unroll
        for (int pl = 0; pl < 5; ++pl)
            #pragma unroll
            for (int j = 0; j < 4; ++j) p[pl][j] = 0ull;

        __syncthreads();
        for (int k = 1; k <= 20; ++k) {
            u64 h[4];
            #pragma unroll
            for (int j = 0; j < 4; ++j) {
                u64 lf = (c[j] << 1) | (j > 0 ? (c[j - 1] >> 63) : 0ull);
                u64 rt = (c[j] >> 1) | (j < 3 ? (c[j + 1] << 63) : 0ull);
                h[j] = c[j] | lf | rt;
                tmp[t][j] = h[j];
            }
            __syncthreads();
            #pragma unroll
            for (int j = 0; j < 4; ++j) {
                u64 u_ = (t > 0)   ? tmp[t - 1][j] : 0ull;
                u64 d_ = (t < 255) ? tmp[t + 1][j] : 0ull;
                u64 n = h[j] | u_ | d_;
                u64 nw = n & ~c[j];
                c[j] = n;
                #pragma unroll
                for (int pl = 0; pl < 5; ++pl)
                    if ((k >> pl) & 1) p[pl][j] |= nw;
            }
            int done = ((c[0] & c[1] & c[2] & c[3]) == 0xFFFFFFFFFFFFFFFFull) ? 1 : 0;
            if (__syncthreads_and(done)) break;
        }

        // never-covered => d0 = 21 (0b10101)
        #pragma unroll
        for (int j = 0; j < 4; ++j) {
            u64 u_ = ~c[j];
            p[0][j] |= u_; p[2][j] |= u_; p[4][j] |= u_;
        }
        #pragma unroll
        for (int pl = 0; pl < 5; ++pl)
            #pragma unroll
            for (int j = 0; j < 4; ++j)
                planes[(size_t)pl * TOTAL_WORDS + (size_t)blockIdx.x * WPS + t * 4 + j] = p[pl][j];
        __threadfence();
    }
    grid.sync();

    // ---- phase C: weighted reduction; thread tid covers exactly word tid ----
    if (t < 22) wtab[t] = 2.0f / (1.0f + __expf(10.0f * (float)(t + 1) * (1.0f / 22.0f)));
    __syncthreads();
    {
        u64 p0 = planes[tid];
        u64 p1 = planes[TOTAL_WORDS + tid];
        u64 p2 = planes[2 * TOTAL_WORDS + tid];
        u64 p3 = planes[3 * TOTAL_WORDS + tid];
        u64 p4 = planes[4 * TOTAL_WORDS + tid];
        const float4* op = (const float4*)outputs + (size_t)tid * 16;

        float s0 = 0.0f, s1 = 0.0f, s2 = 0.0f;
        #pragma unroll
        for (int j = 0; j < 16; ++j) {
            float4 o4 = op[j];
            float ov[4] = {o4.x, o4.y, o4.z, o4.w};
            #pragma unroll
            for (int q = 0; q < 4; ++q) {
                int sh = j * 4 + q;
                int d0 = (int)((p0 >> sh) & 1ull)
                       | ((int)((p1 >> sh) & 1ull) << 1)
                       | ((int)((p2 >> sh) & 1ull) << 2)
                       | ((int)((p3 >> sh) & 1ull) << 3)
                       | ((int)((p4 >> sh) & 1ull) << 4);
                float w = wtab[d0];
                float ow = ov[q] * w;
                float mb = (float)((mword >> sh) & 1ull);
                s0 += ow;            // sum(outputs*w)
                s1 += mb * w;        // sum(m*w)
                s2 += mb * ow;       // sum(outputs*w*m)
            }
        }
        float sv[3] = {s0, s1, s2};
        #pragma unroll
        for (int k = 0; k < 3; ++k) {
            float v = sv[k];
            #pragma unroll
            for (int off = 32; off > 0; off >>= 1) v += __shfl_down(v, off);
            sv[k] = v;
        }
        if (lane == 0) { red[wv][0] = sv[0]; red[wv][1] = sv[1]; red[wv][2] = sv[2]; }
        __syncthreads();
        if (t < 3) partials[blockIdx.x * 3 + t] =
            red[0][t] + red[1][t] + red[2][t] + red[3][t];
        __threadfence();
    }
    grid.sync();

    // ---- phase D: block 0 reduces 512 partial-triples, computes loss ----
    if (blockIdx.x == 0) {
        float s[6];
        #pragma unroll
        for (int k = 0; k < 3; ++k) {
            s[k]     = partials[t * 3 + k];           // blocks 0..255  -> batch 0
            s[3 + k] = partials[(t + 256) * 3 + k];   // blocks 256..511 -> batch 1
        }
        #pragma unroll
        for (int k = 0; k < 6; ++k) {
            float v = s[k];
            #pragma unroll
            for (int off = 32; off > 0; off >>= 1) v += __shfl_down(v, off);
            s[k] = v;
        }
        if (lane == 0) {
            #pragma unroll
            for (int k = 0; k < 6; ++k) red[wv][k] = s[k];
        }
        __syncthreads();
        if (t == 0) {
            float loss = 0.0f;
            #pragma unroll
            for (int b = 0; b < 2; ++b) {
                float A = red[0][b*3+0] + red[1][b*3+0] + red[2][b*3+0] + red[3][b*3+0];
                float T = red[0][b*3+1] + red[1][b*3+1] + red[2][b*3+1] + red[3][b*3+1];
                float I = red[0][b*3+2] + red[1][b*3+2] + red[2][b*3+2] + red[3][b*3+2];
                loss += (T == 0.0f) ? 0.0f : (1.0f - 2.0f * I / (A + T + 2e-6f));
            }
            out[0] = 0.5f * loss;
        }
    }
}

extern "C" void kernel_launch(void* const* d_in, const int* in_sizes, int n_in,
                              void* d_out, int out_size, void* d_ws, size_t ws_size,
                              hipStream_t stream) {
    const float* outputs = (const float*)d_in[0];
    const int* masks = (const int*)d_in[1];
    float* out = (float*)d_out;

    u64* mbits = (u64*)d_ws;
    u64* planes = mbits + TOTAL_WORDS;
    float* partials = (float*)(planes + 5 * TOTAL_WORDS);

    void* args[] = {(void*)&outputs, (void*)&masks, (void*)&mbits,
                    (void*)&planes, (void*)&partials, (void*)&out};
    hipLaunchCooperativeKernel((const void*)bbsd_all, dim3(NBLK), dim3(256),
                               args, 0, stream);
}

// Round 4
// 120.881 us; speedup vs baseline: 2.7699x; 2.7699x over previous
//
#include <hip/hip_runtime.h>
#include <stdint.h>

typedef unsigned long long u64;
typedef unsigned int u32;

// One self-contained kernel. Block = (slice, column-half): packs its slice's
// mask to bits, computes edge + cascaded 3x3 dilation (d0 = first-set round
// = Chebyshev distance to nearest edge; sum_k dilate^k = max(0,21-d0)),
// keeps the 5 d0 bit-planes in row-owner registers, reduces its half of
// outputs, atomically accumulates 6 sums, last block computes the loss.
// No grid sync (R3 showed cg::grid().sync costs ~65us/sync on gfx950).
__global__ __launch_bounds__(256) void bbsd_fused(const float* __restrict__ outputs,
                                                  const int* __restrict__ masks,
                                                  float* __restrict__ acc,      // 6 floats, pre-zeroed
                                                  u32* __restrict__ cnt,        // pre-zeroed
                                                  float* __restrict__ out) {
    __shared__ u64 rows[256][5];   // mask bits per row (+pad col) — stays = mask
    __shared__ u64 tmp[256][5];    // dilation exchange
    __shared__ float wtab[22];
    __shared__ float red[4][3];

    const int t = threadIdx.x;              // row this thread owns
    const int lane = t & 63, wv = t >> 6;
    const int slice = blockIdx.x & 127;     // pair (s, s+128) lands on same XCD
    const int h = blockIdx.x >> 7;          // column half: 0 -> cols 0..127, 1 -> 128..255
    const int b = slice >> 6;               // batch

    if (t < 22) wtab[t] = 2.0f / (1.0f + __expf(10.0f * (float)(t + 1) * (1.0f / 22.0f)));

    // ---- pack row t: 64 independent int4 loads -> 4 u64 words ----
    u64 m[4] = {0ull, 0ull, 0ull, 0ull};
    {
        const int4* mp = (const int4*)(masks + (size_t)slice * 65536 + (size_t)t * 256);
        #pragma unroll
        for (int g = 0; g < 64; ++g) {
            int4 v = mp[g];
            u64 nib = (u64)(v.x != 0) | ((u64)(v.y != 0) << 1)
                    | ((u64)(v.z != 0) << 2) | ((u64)(v.w != 0) << 3);
            m[g >> 4] |= nib << ((g & 15) * 4);
        }
        #pragma unroll
        for (int j = 0; j < 4; ++j) rows[t][j] = m[j];
    }
    __syncthreads();

    // ---- edge = m & ~(up & dn & lf & rt), zero-padded ----
    u64 c[4];
    {
        u64 up[4], dn[4];
        #pragma unroll
        for (int j = 0; j < 4; ++j) {
            up[j] = (t > 0)   ? rows[t - 1][j] : 0ull;
            dn[j] = (t < 255) ? rows[t + 1][j] : 0ull;
        }
        #pragma unroll
        for (int j = 0; j < 4; ++j) {
            u64 lf = (m[j] << 1) | (j > 0 ? (m[j - 1] >> 63) : 0ull);
            u64 rt = (m[j] >> 1) | (j < 3 ? (m[j + 1] << 63) : 0ull);
            c[j] = m[j] & ~(up[j] & dn[j] & lf & rt);
        }
    }

    // ---- cascaded dilation, record d0 as 5 register bit-planes ----
    u64 p[5][4];
    #pragma unroll
    for (int pl = 0; pl < 5; ++pl)
        #pragma unroll
        for (int j = 0; j < 4; ++j) p[pl][j] = 0ull;

    for (int k = 1; k <= 20; ++k) {
        u64 hh[4];
        #pragma unroll
        for (int j = 0; j < 4; ++j) {
            u64 lf = (c[j] << 1) | (j > 0 ? (c[j - 1] >> 63) : 0ull);
            u64 rt = (c[j] >> 1) | (j < 3 ? (c[j + 1] << 63) : 0ull);
            hh[j] = c[j] | lf | rt;
            tmp[t][j] = hh[j];
        }
        __syncthreads();
        #pragma unroll
        for (int j = 0; j < 4; ++j) {
            u64 u_ = (t > 0)   ? tmp[t - 1][j] : 0ull;
            u64 d_ = (t < 255) ? tmp[t + 1][j] : 0ull;
            u64 n = hh[j] | u_ | d_;
            u64 nw = n & ~c[j];
            c[j] = n;
            #pragma unroll
            for (int pl = 0; pl < 5; ++pl) {
                u64 sel = (u64)0 - (u64)((k >> pl) & 1);   // branchless, k wave-uniform
                p[pl][j] |= nw & sel;
            }
        }
        int done = ((c[0] & c[1] & c[2] & c[3]) == 0xFFFFFFFFFFFFFFFFull) ? 1 : 0;
        if (__syncthreads_and(done)) break;   // also protects tmp reuse
    }

    // never covered within 20 rounds => d0 = 21 (0b10101)
    #pragma unroll
    for (int j = 0; j < 4; ++j) {
        u64 u_ = ~c[j];
        p[0][j] |= u_; p[2][j] |= u_; p[4][j] |= u_;
    }

    // ---- reduce: thread t handles row t, columns [h*128, h*128+128) ----
    float s0 = 0.0f, s1 = 0.0f, s2 = 0.0f;
    {
        const float4* op4 = (const float4*)(outputs + (size_t)slice * 65536
                                            + (size_t)t * 256 + h * 128);
        #pragma unroll
        for (int i = 0; i < 32; ++i) {
            float4 o4 = op4[i];
            const int w = 2 * h + (i >> 4);
            const int sh = (i & 15) * 4;
            u32 P0 = (u32)(p[0][w] >> sh), P1 = (u32)(p[1][w] >> sh);
            u32 P2 = (u32)(p[2][w] >> sh), P3 = (u32)(p[3][w] >> sh);
            u32 P4 = (u32)(p[4][w] >> sh), M  = (u32)(m[w] >> sh);
            float ov[4] = {o4.x, o4.y, o4.z, o4.w};
            #pragma unroll
            for (int q = 0; q < 4; ++q) {
                int d0 = (int)((P0 >> q) & 1u)
                       | ((int)((P1 >> q) & 1u) << 1)
                       | ((int)((P2 >> q) & 1u) << 2)
                       | ((int)((P3 >> q) & 1u) << 3)
                       | ((int)((P4 >> q) & 1u) << 4);
                float wgt = wtab[d0];                    // mostly broadcast (d0 in {0,1,2})
                float wm = ((M >> q) & 1u) ? wgt : 0.0f;
                s0 += ov[q] * wgt;   // sum(outputs*w)
                s1 += wm;            // sum(m*w)
                s2 += ov[q] * wm;    // sum(outputs*w*m)
            }
        }
    }

    // ---- block reduce + device accumulate ----
    #pragma unroll
    for (int off = 32; off > 0; off >>= 1) {
        s0 += __shfl_down(s0, off);
        s1 += __shfl_down(s1, off);
        s2 += __shfl_down(s2, off);
    }
    if (lane == 0) { red[wv][0] = s0; red[wv][1] = s1; red[wv][2] = s2; }
    __syncthreads();
    if (t < 3) {
        float v = red[0][t] + red[1][t] + red[2][t] + red[3][t];
        atomicAdd(&acc[b * 3 + t], v);
        __threadfence();
    }
    __syncthreads();

    // ---- last block finalizes ----
    if (t == 0) {
        u32 old = __hip_atomic_fetch_add(cnt, 1u, __ATOMIC_ACQ_REL, __HIP_MEMORY_SCOPE_AGENT);
        if (old == 255u) {
            float s[6];
            #pragma unroll
            for (int k = 0; k < 6; ++k)
                s[k] = __hip_atomic_load(&acc[k], __ATOMIC_ACQUIRE, __HIP_MEMORY_SCOPE_AGENT);
            float loss = 0.0f;
            #pragma unroll
            for (int bb = 0; bb < 2; ++bb) {
                float A = s[bb * 3 + 0], T = s[bb * 3 + 1], I = s[bb * 3 + 2];
                loss += (T == 0.0f) ? 0.0f : (1.0f - 2.0f * I / (A + T + 2e-6f));
            }
            out[0] = 0.5f * loss;
        }
    }
}

extern "C" void kernel_launch(void* const* d_in, const int* in_sizes, int n_in,
                              void* d_out, int out_size, void* d_ws, size_t ws_size,
                              hipStream_t stream) {
    const float* outputs = (const float*)d_in[0];
    const int* masks = (const int*)d_in[1];
    float* out = (float*)d_out;
    float* acc = (float*)d_ws;                       // 6 floats
    u32* cnt = (u32*)((char*)d_ws + 24);             // 1 counter

    hipMemsetAsync(d_ws, 0, 32, stream);
    bbsd_fused<<<256, 256, 0, stream>>>(outputs, masks, acc, cnt, out);
}